// Round 8
// baseline (8503.164 us; speedup 1.0000x reference)
//
#include <hip/hip_runtime.h>
#include <stdint.h>

typedef unsigned short u16;
typedef __attribute__((ext_vector_type(4))) float f32x4;
typedef __attribute__((ext_vector_type(4))) uint32_t u32x4;
typedef __attribute__((ext_vector_type(8))) short bf16x8;

#define DEV __device__ __forceinline__
#define NWG 64

DEV u16 f2bf(float f) {
  union { float f; uint32_t u; } v; v.f = f;
  uint32_t r = (v.u + 0x7FFFu + ((v.u >> 16) & 1u)) >> 16;  // RNE
  return (u16)r;
}
DEV float bf2f(u16 h) {
  union { uint32_t u; float f; } v; v.u = ((uint32_t)h) << 16;
  return v.f;
}
DEV float sigmoidf(float x) { return 1.0f / (1.0f + expf(-x)); }
DEV uint32_t umin2(uint32_t a, uint32_t b) { return a < b ? a : b; }

// async global->LDS, 16B per lane; lds base must be wave-uniform (HW adds lane*16)
DEV void gll16(const void* g, void* l) {
  __builtin_amdgcn_global_load_lds((__attribute__((address_space(1))) void*)g,
                                   (__attribute__((address_space(3))) void*)l,
                                   16, 0, 0);
}

// coherent 16B u32x4 load: sc0 sc1 bypass L1/L2 (cross-XCD safe).
// NOTE: does NOT wait — caller must s_waitcnt vmcnt(0) + sched_barrier(0)
// before reading the result (rule #18: compiler can't see the data dep).
DEV u32x4 ldgu16(const uint32_t* p) {
  u32x4 r;
  asm volatile("global_load_dwordx4 %0, %1, off sc0 sc1"
               : "=&v"(r) : "v"(p) : "memory");
  return r;
}

// ---------------------------------------------------------------------------
// prep kernels
// ---------------------------------------------------------------------------
__global__ void convert_bf16_kernel(const float* __restrict__ in, u16* __restrict__ out, int n) {
  int i = (blockIdx.x * blockDim.x + threadIdx.x) * 4;
  if (i + 3 < n) {
    f32x4 v = *(const f32x4*)(in + i);
    uint64_t pk = (uint64_t)f2bf(v[0]) | ((uint64_t)f2bf(v[1]) << 16) |
                  ((uint64_t)f2bf(v[2]) << 32) | ((uint64_t)f2bf(v[3]) << 48);
    *(uint64_t*)(out + i) = pk;
  }
}

// out(C,R) bf16 = transpose(in(R,C) f32); R,C multiples of 32
__global__ __launch_bounds__(1024) void transpose_to_bf16(
    const float* __restrict__ in, u16* __restrict__ out, int R, int C) {
  __shared__ float tl[32][33];
  const int tx = threadIdx.x, ty = threadIdx.y;
  const int c0 = blockIdx.x * 32, r0 = blockIdx.y * 32;
  tl[ty][tx] = in[(size_t)(r0 + ty) * C + c0 + tx];
  __syncthreads();
  out[(size_t)(c0 + ty) * R + r0 + tx] = f2bf(tl[tx][ty]);
}

// ---------------------------------------------------------------------------
// GEMM: C(MxN) = A(MxK,bf16) @ Bt(NxK,bf16)^T   (m97 structure, 128x128, BK=64)
// mode 0: write Cf(f32) + Cb(bf16), no bias
// mode 1: write Cb(bf16), +bias
// mode 2: write Cf(f32), +bias
// ---------------------------------------------------------------------------
__global__ __launch_bounds__(256) void gemm_bt_kernel(
    const u16* __restrict__ A, const u16* __restrict__ Bt,
    const float* __restrict__ bias,
    float* __restrict__ Cf, u16* __restrict__ Cb,
    int M, int N, int K, int mode) {
  __shared__ u16 As[128 * 64];
  __shared__ u16 Bs[128 * 64];
  const int tid  = threadIdx.x;
  const int lane = tid & 63;
  const int wid  = tid >> 6;
  const int wr   = wid >> 1, wc = wid & 1;
  const size_t arow0 = (size_t)blockIdx.y * 128;
  const size_t brow0 = (size_t)blockIdx.x * 128;

  f32x4 acc[4][4];
#pragma unroll
  for (int m = 0; m < 4; ++m)
#pragma unroll
    for (int n = 0; n < 4; ++n) acc[m][n] = (f32x4){0.f, 0.f, 0.f, 0.f};

  for (int k0 = 0; k0 < K; k0 += 64) {
#pragma unroll
    for (int it = 0; it < 4; ++it) {
      const int slot = it * 4 + wid;
      const int ch   = slot * 64 + lane;
      const int r    = ch >> 3;
      const int cc   = (ch & 7) * 8;
      gll16(A  + (arow0 + r) * K + k0 + cc, (void*)(As + slot * 64 * 8));
      gll16(Bt + (brow0 + r) * K + k0 + cc, (void*)(Bs + slot * 64 * 8));
    }
    __syncthreads();
#pragma unroll
    for (int kk = 0; kk < 2; ++kk) {
      const int ro = lane & 15;
      const int ko = kk * 32 + (lane >> 4) * 8;
      bf16x8 av[4], bv[4];
#pragma unroll
      for (int m = 0; m < 4; ++m) av[m] = *(const bf16x8*)(As + (wr * 64 + m * 16 + ro) * 64 + ko);
#pragma unroll
      for (int n = 0; n < 4; ++n) bv[n] = *(const bf16x8*)(Bs + (wc * 64 + n * 16 + ro) * 64 + ko);
#pragma unroll
      for (int m = 0; m < 4; ++m)
#pragma unroll
        for (int n = 0; n < 4; ++n)
          acc[m][n] = __builtin_amdgcn_mfma_f32_16x16x32_bf16(av[m], bv[n], acc[m][n], 0, 0, 0);
    }
    __syncthreads();
  }

  const int rb = (lane >> 4) * 4;
  const int cn = lane & 15;
#pragma unroll
  for (int m = 0; m < 4; ++m) {
#pragma unroll
    for (int n = 0; n < 4; ++n) {
      const size_t col = brow0 + wc * 64 + n * 16 + cn;
      const float badd = (mode != 0) ? bias[col] : 0.f;
#pragma unroll
      for (int r = 0; r < 4; ++r) {
        const size_t row = arow0 + wr * 64 + m * 16 + rb + r;
        const float v = acc[m][n][r] + badd;
        if (mode == 0) { Cf[row * N + col] = v; Cb[row * N + col] = f2bf(v); }
        else if (mode == 1) { Cb[row * N + col] = f2bf(v); }
        else { Cf[row * N + col] = v; }
      }
    }
  }
}

// ---------------------------------------------------------------------------
// Persistent per-layer LSTM recurrence, integer-tagged data broadcast.
// 64 WGs x 256 thr, 1 WG/CU. Wave w holds gate w's 16 Wr rows in regs.
// h exchanged via u32 panel[2][32][1024]: entry = ((s+1)<<16) | bf16(h),
// s = l*256+t (monotone within launch, <=1024 fits 16 bits). Consumers
// poll raw values until min >= (s<<16): the data IS the flag, bf16 payload
// is exact. No producer store-ack drain, no flag RTT. 2 barriers/step.
// ---------------------------------------------------------------------------
__global__ __launch_bounds__(256, 1) void lstm_layer_kernel(
    const u16* __restrict__ xgb, const float* __restrict__ xgf, int xg32,
    const u16* __restrict__ wrT,      // (4096,1024) bf16, layer slice
    uint32_t* __restrict__ panel,     // [2][32][1024] u32 tagged h exchange
    u16* __restrict__ ys,             // (B*T,1024) bf16 layer output (write-only here)
    float* __restrict__ out,          // (2,L,B,U) f32
    int l) {
  __shared__ __align__(16) u16 Hs[32 * 1024];   // 64 KB h panel (bf16, swizzled)
  __shared__ float gl[4][32][17];               // padded gate-exchange

  const int tid  = threadIdx.x;
  const int lane = tid & 63;
  const int w    = tid >> 6;          // gate id
  const int u0   = blockIdx.x * 16;
  const int r0   = lane & 15;
  const int hi   = lane >> 4;
  const int rb   = hi * 4;
  const int gb   = tid >> 3;          // gate-phase batch row 0..31
  const int j0   = (tid & 7) * 2;     // gate-phase unit pair

  // ---- one-time: B fragments (gate w, units u0+r0, all K) -> registers ----
  bf16x8 breg[32];
#pragma unroll
  for (int kk = 0; kk < 32; ++kk)
    breg[kk] = *(const bf16x8*)(wrT + ((size_t)w * 1024 + u0 + r0) * 1024 + kk * 32 + hi * 8);

  float c0 = 0.f, c1 = 0.f;           // cell state for (gb,j0),(gb,j0+1)
  float xv[8], xvn[8];
#pragma unroll
  for (int m = 0; m < 2; ++m)
#pragma unroll
    for (int r = 0; r < 4; ++r) {
      const size_t off = ((size_t)((m * 16 + rb + r) * 256 + 0)) * 4096 +
                         (size_t)w * 1024 + u0 + r0;
      xv[m * 4 + r] = xg32 ? xgf[off] : bf2f(xgb[off]);
    }

  for (int t = 0; t < 256; ++t) {
    const int s = l * 256 + t;

    // xg prefetch for t+1 at iteration top: a whole step of latency slack
    if (t < 255) {
#pragma unroll
      for (int m = 0; m < 2; ++m)
#pragma unroll
        for (int r = 0; r < 4; ++r) {
          const size_t off = ((size_t)((m * 16 + rb + r) * 256 + t + 1)) * 4096 +
                             (size_t)w * 1024 + u0 + r0;
          xvn[m * 4 + r] = xg32 ? xgf[off] : bf2f(xgb[off]);
        }
    }

    f32x4 acc0 = (f32x4){0.f, 0.f, 0.f, 0.f};
    f32x4 acc1 = acc0;

    if (t > 0) {
      const uint32_t sTag = (uint32_t)s << 16;    // fresh tag = s (from step s-1)
      const uint32_t* Pb  = panel + (size_t)((s - 1) & 1) * 32768;

      // issue all 32 gather loads (128 KB/WG from coherence point)
      u32x4 va[16], vb[16];
#pragma unroll
      for (int k = 0; k < 16; ++k) {
        const int g   = k * 256 + tid;      // granule-pair id: 8 u32 each
        const int row = g >> 7;             // batch 0..31
        const int q   = g & 127;            // 8-unit group within row
        const uint32_t* P = Pb + row * 1024 + q * 8;
        va[k] = ldgu16(P);
        vb[k] = ldgu16(P + 4);
      }
      asm volatile("s_waitcnt vmcnt(0)" ::: "memory");
      __builtin_amdgcn_sched_barrier(0);

      // validate per granule-pair (retry stale), pack bf16, stage into LDS
#pragma unroll
      for (int k = 0; k < 16; ++k) {
        const int g   = k * 256 + tid;
        const int row = g >> 7;
        const int q   = g & 127;
        const uint32_t* P = Pb + row * 1024 + q * 8;
        while (true) {
          uint32_t mn = umin2(umin2(umin2(va[k].x, va[k].y), umin2(va[k].z, va[k].w)),
                              umin2(umin2(vb[k].x, vb[k].y), umin2(vb[k].z, vb[k].w)));
          if (!__any(mn < sTag)) break;     // tag dominates compare
          __builtin_amdgcn_s_sleep(1);
          va[k] = ldgu16(P);
          vb[k] = ldgu16(P + 4);
          asm volatile("s_waitcnt vmcnt(0)" ::: "memory");
          __builtin_amdgcn_sched_barrier(0);
        }
        u32x4 pk;
        pk.x = (va[k].x & 0xFFFFu) | (va[k].y << 16);
        pk.y = (va[k].z & 0xFFFFu) | (va[k].w << 16);
        pk.z = (vb[k].x & 0xFFFFu) | (vb[k].y << 16);
        pk.w = (vb[k].z & 0xFFFFu) | (vb[k].w << 16);
        *(u32x4*)(Hs + (size_t)row * 1024 + (size_t)(q ^ (row & 7)) * 8) = pk;
      }
      __syncthreads();   // B1: A panel staged

      // ---- MFMA: A from LDS (swizzled read), B from registers ----
#pragma unroll
      for (int kk = 0; kk < 32; ++kk) {
        const int q  = kk * 4 + hi;
        const int sw = (q ^ (r0 & 7)) * 8;
        bf16x8 a0 = *(const bf16x8*)(Hs + (size_t)r0 * 1024 + sw);
        bf16x8 a1 = *(const bf16x8*)(Hs + (size_t)(16 + r0) * 1024 + sw);
        acc0 = __builtin_amdgcn_mfma_f32_16x16x32_bf16(a0, breg[kk], acc0, 0, 0, 0);
        acc1 = __builtin_amdgcn_mfma_f32_16x16x32_bf16(a1, breg[kk], acc1, 0, 0, 0);
      }
    }

    // D frag -> gl: col=lane&15 (unit j), row=(lane>>4)*4+reg (batch)
#pragma unroll
    for (int m = 0; m < 2; ++m) {
      f32x4 a = m ? acc1 : acc0;
#pragma unroll
      for (int r = 0; r < 4; ++r)
        gl[w][m * 16 + rb + r][r0] = a[r] + xv[m * 4 + r];
    }
    __syncthreads();   // B2: gl complete across gates (also fences Hs reads)

    // gates + cell update (c in regs) + tagged publish (fire-and-forget)
    float hv[2];
#pragma unroll
    for (int jj = 0; jj < 2; ++jj) {
      const int j = j0 + jj;
      const float gi = gl[0][gb][j];
      const float gf = gl[1][gb][j];
      const float gc = gl[2][gb][j];
      const float go = gl[3][gb][j];
      const float i_ = sigmoidf(gi), f_ = sigmoidf(gf);
      const float cd = tanhf(gc),   o_ = sigmoidf(go);
      float& c = jj ? c1 : c0;
      c = f_ * c + i_ * cd;
      hv[jj] = o_ * tanhf(c);
      if (t == 255) {
        out[(size_t)l * 32768 + (size_t)gb * 1024 + u0 + j]       = hv[jj];
        out[(size_t)(4 + l) * 32768 + (size_t)gb * 1024 + u0 + j] = c;
      }
    }
    const u16 hb0 = f2bf(hv[0]), hb1 = f2bf(hv[1]);
    {  // tagged u32 pair -> panel slot s&1 (8B atomic store, agent scope)
      const uint32_t tagv = (uint32_t)(s + 1) << 16;
      const uint64_t pk = (uint64_t)(tagv | hb0) | ((uint64_t)(tagv | hb1) << 32);
      __hip_atomic_store((uint64_t*)(panel + (size_t)(s & 1) * 32768 + gb * 1024 + u0 + j0),
                         pk, __ATOMIC_RELAXED, __HIP_MEMORY_SCOPE_AGENT);
    }
    // plain bf16 store for the residual path (read after kernel end)
    *(uint32_t*)(ys + ((size_t)(gb * 256 + t)) * 1024 + u0 + j0) =
        (uint32_t)hb0 | ((uint32_t)hb1 << 16);

#pragma unroll
    for (int i = 0; i < 8; ++i) xv[i] = xvn[i];
  }
}

// seq += ys (residual); refresh bf16 copy of seq
__global__ void seq_update_kernel(float* __restrict__ seqf, u16* __restrict__ seqb,
                                  const u16* __restrict__ ys, int n) {
  int i = (blockIdx.x * blockDim.x + threadIdx.x) * 4;
  if (i + 3 < n) {
    f32x4 s = *(f32x4*)(seqf + i);
    uint64_t yv = *(const uint64_t*)(ys + i);
    s[0] += bf2f((u16)(yv & 0xFFFF));
    s[1] += bf2f((u16)((yv >> 16) & 0xFFFF));
    s[2] += bf2f((u16)((yv >> 32) & 0xFFFF));
    s[3] += bf2f((u16)((yv >> 48) & 0xFFFF));
    *(f32x4*)(seqf + i) = s;
    uint64_t pk = (uint64_t)f2bf(s[0]) | ((uint64_t)f2bf(s[1]) << 16) |
                  ((uint64_t)f2bf(s[2]) << 32) | ((uint64_t)f2bf(s[3]) << 48);
    *(uint64_t*)(seqb + i) = pk;
  }
}

// ---------------------------------------------------------------------------
extern "C" void kernel_launch(void* const* d_in, const int* in_sizes, int n_in,
                              void* d_out, int out_size, void* d_ws, size_t ws_size,
                              hipStream_t stream) {
  const float* x     = (const float*)d_in[0];   // (32,256,512)
  const float* Wskip = (const float*)d_in[1];   // (512,1024)
  const float* Wk    = (const float*)d_in[2];   // (4,1024,4096)
  const float* Wr    = (const float*)d_in[3];   // (4,1024,4096)
  const float* bias  = (const float*)d_in[4];   // (4,4096)
  float* out = (float*)d_out;

  char* ws = (char*)d_ws;
  size_t o = 0;
  auto carve = [&](size_t bytes) -> char* {
    char* p = ws + o;
    o += (bytes + 255) & ~(size_t)255;
    return p;
  };
  u16*      xbf   = (u16*)     carve((size_t)8192 * 512 * 2);
  u16*      wskT  = (u16*)     carve((size_t)1024 * 512 * 2);
  u16*      wkT   = (u16*)     carve((size_t)4 * 4096 * 1024 * 2);
  u16*      wrT   = (u16*)     carve((size_t)4 * 4096 * 1024 * 2);
  float*    seqf  = (float*)   carve((size_t)8192 * 1024 * 4);
  u16*      seqb  = (u16*)     carve((size_t)8192 * 1024 * 2);
  u16*      ysb   = (u16*)     carve((size_t)8192 * 1024 * 2);
  uint32_t* panel = (uint32_t*)carve((size_t)2 * 32 * 1024 * 4);
  // xg: prefer f32 storage (accuracy) if workspace allows; else bf16
  const int xg32 = (ws_size >= o + (size_t)8192 * 4096 * 4 + 512) ? 1 : 0;
  float* xgf = nullptr;
  u16*   xgb = nullptr;
  if (xg32) xgf = (float*)carve((size_t)8192 * 4096 * 4);
  else      xgb = (u16*)  carve((size_t)8192 * 4096 * 2);

  // ---- prep ----
  hipMemsetAsync(panel, 0, (size_t)2 * 32 * 1024 * 4, stream);  // reset tags per launch
  convert_bf16_kernel<<<4096, 256, 0, stream>>>(x, xbf, 8192 * 512);
  dim3 tb(32, 32);
  transpose_to_bf16<<<dim3(1024 / 32, 512 / 32), tb, 0, stream>>>(Wskip, wskT, 512, 1024);
  for (int l = 0; l < 4; ++l) {
    transpose_to_bf16<<<dim3(4096 / 32, 1024 / 32), tb, 0, stream>>>(
        Wk + (size_t)l * 1024 * 4096, wkT + (size_t)l * 4096 * 1024, 1024, 4096);
    transpose_to_bf16<<<dim3(4096 / 32, 1024 / 32), tb, 0, stream>>>(
        Wr + (size_t)l * 1024 * 4096, wrT + (size_t)l * 4096 * 1024, 1024, 4096);
  }

  // ---- skip projection: seq = x @ W_skip ----
  gemm_bt_kernel<<<dim3(1024 / 128, 8192 / 128), 256, 0, stream>>>(
      xbf, wskT, nullptr, seqf, seqb, 8192, 1024, 512, 0);

  // ---- layers ----
  for (int l = 0; l < 4; ++l) {
    gemm_bt_kernel<<<dim3(4096 / 128, 8192 / 128), 256, 0, stream>>>(
        seqb, wkT + (size_t)l * 4096 * 1024, bias + (size_t)l * 4096,
        xgf, xgb, 8192, 4096, 1024, xg32 ? 2 : 1);
    lstm_layer_kernel<<<NWG, 256, 0, stream>>>(xgb, xgf, xg32,
                                               wrT + (size_t)l * 4096 * 1024,
                                               panel, ysb, out, l);
    if (l < 3)
      seq_update_kernel<<<8192, 256, 0, stream>>>(seqf, seqb, ysb, 8192 * 1024);
  }
}

// Round 11
// 4657.132 us; speedup vs baseline: 1.8258x; 1.8258x over previous
//
#include <hip/hip_runtime.h>
#include <stdint.h>

typedef unsigned short u16;
typedef __attribute__((ext_vector_type(2))) float f32x2;
typedef __attribute__((ext_vector_type(4))) float f32x4;
typedef __attribute__((ext_vector_type(2))) uint32_t u32x2;
typedef __attribute__((ext_vector_type(4))) uint32_t u32x4;
typedef __attribute__((ext_vector_type(8))) short bf16x8;

#define DEV __device__ __forceinline__

DEV u16 f2bf(float f) {
  union { float f; uint32_t u; } v; v.f = f;
  uint32_t r = (v.u + 0x7FFFu + ((v.u >> 16) & 1u)) >> 16;  // RNE
  return (u16)r;
}
DEV float bf2f(u16 h) {
  union { uint32_t u; float f; } v; v.u = ((uint32_t)h) << 16;
  return v.f;
}
DEV uint32_t f2u(float f) { union { float f; uint32_t u; } v; v.f = f; return v.u; }
DEV float u2f(uint32_t u) { union { uint32_t u; float f; } v; v.u = u; return v.f; }
DEV float sigmoidf(float x) { return 1.0f / (1.0f + expf(-x)); }
DEV uint32_t umin2(uint32_t a, uint32_t b) { return a < b ? a : b; }

// async global->LDS, 16B/lane; lds base wave-uniform (HW adds lane*16)
DEV void gll16(const void* g, void* l) {
  __builtin_amdgcn_global_load_lds((__attribute__((address_space(1))) void*)g,
                                   (__attribute__((address_space(3))) void*)l,
                                   16, 0, 0);
}
// coherent loads (sc0 sc1: bypass L1/L2, read device coherence point).
// Caller MUST s_waitcnt vmcnt(0) + sched_barrier(0) before consuming (rule #18).
DEV u32x4 ldg4u(const void* p) {
  u32x4 r;
  asm volatile("global_load_dwordx4 %0, %1, off sc0 sc1" : "=&v"(r) : "v"(p) : "memory");
  return r;
}
DEV u32x2 ldg2u(const void* p) {
  u32x2 r;
  asm volatile("global_load_dwordx2 %0, %1, off sc0 sc1" : "=&v"(r) : "v"(p) : "memory");
  return r;
}
// pack 2 f32 -> 2 bf16 (lo in low half)
DEV uint32_t cvt2(float lo, float hi) {
  uint32_t r;
  asm("v_cvt_pk_bf16_f32 %0, %1, %2" : "=v"(r) : "v"(lo), "v"(hi));
  return r;
}

// ---------------------------------------------------------------------------
// prep kernels
// ---------------------------------------------------------------------------
__global__ void convert_bf16_kernel(const float* __restrict__ in, u16* __restrict__ out, int n) {
  int i = (blockIdx.x * blockDim.x + threadIdx.x) * 4;
  if (i + 3 < n) {
    f32x4 v = *(const f32x4*)(in + i);
    uint64_t pk = (uint64_t)f2bf(v[0]) | ((uint64_t)f2bf(v[1]) << 16) |
                  ((uint64_t)f2bf(v[2]) << 32) | ((uint64_t)f2bf(v[3]) << 48);
    *(uint64_t*)(out + i) = pk;
  }
}

__global__ __launch_bounds__(1024) void transpose_to_bf16(
    const float* __restrict__ in, u16* __restrict__ out, int R, int C) {
  __shared__ float tl[32][33];
  const int tx = threadIdx.x, ty = threadIdx.y;
  const int c0 = blockIdx.x * 32, r0 = blockIdx.y * 32;
  tl[ty][tx] = in[(size_t)(r0 + ty) * C + c0 + tx];
  __syncthreads();
  out[(size_t)(c0 + ty) * R + r0 + tx] = f2bf(tl[tx][ty]);
}

// ---------------------------------------------------------------------------
// Skip GEMM: C = A(8192x512) @ Wskip^T -> Cf f32 with low 10 bits masked to 0
// (clean tag field for the seq protocol) + Cb bf16 mirror.
// ---------------------------------------------------------------------------
__global__ __launch_bounds__(256) void gemm_bt_kernel(
    const u16* __restrict__ A, const u16* __restrict__ Bt,
    float* __restrict__ Cf, u16* __restrict__ Cb, int M, int N, int K) {
  __shared__ u16 As[128 * 64];
  __shared__ u16 Bs[128 * 64];
  const int tid  = threadIdx.x;
  const int lane = tid & 63;
  const int wid  = tid >> 6;
  const int wr   = wid >> 1, wc = wid & 1;
  const size_t arow0 = (size_t)blockIdx.y * 128;
  const size_t brow0 = (size_t)blockIdx.x * 128;

  f32x4 acc[4][4];
#pragma unroll
  for (int m = 0; m < 4; ++m)
#pragma unroll
    for (int n = 0; n < 4; ++n) acc[m][n] = (f32x4){0.f, 0.f, 0.f, 0.f};

  for (int k0 = 0; k0 < K; k0 += 64) {
#pragma unroll
    for (int it = 0; it < 4; ++it) {
      const int slot = it * 4 + wid;
      const int ch   = slot * 64 + lane;
      const int r    = ch >> 3;
      const int cc   = (ch & 7) * 8;
      gll16(A  + (arow0 + r) * K + k0 + cc, (void*)(As + slot * 64 * 8));
      gll16(Bt + (brow0 + r) * K + k0 + cc, (void*)(Bs + slot * 64 * 8));
    }
    __syncthreads();
#pragma unroll
    for (int kk = 0; kk < 2; ++kk) {
      const int ro = lane & 15;
      const int ko = kk * 32 + (lane >> 4) * 8;
      bf16x8 av[4], bv[4];
#pragma unroll
      for (int m = 0; m < 4; ++m) av[m] = *(const bf16x8*)(As + (wr * 64 + m * 16 + ro) * 64 + ko);
#pragma unroll
      for (int n = 0; n < 4; ++n) bv[n] = *(const bf16x8*)(Bs + (wc * 64 + n * 16 + ro) * 64 + ko);
#pragma unroll
      for (int m = 0; m < 4; ++m)
#pragma unroll
        for (int n = 0; n < 4; ++n)
          acc[m][n] = __builtin_amdgcn_mfma_f32_16x16x32_bf16(av[m], bv[n], acc[m][n], 0, 0, 0);
    }
    __syncthreads();
  }

  const int rb = (lane >> 4) * 4;
  const int cn = lane & 15;
#pragma unroll
  for (int m = 0; m < 4; ++m)
#pragma unroll
    for (int n = 0; n < 4; ++n) {
      const size_t col = brow0 + wc * 64 + n * 16 + cn;
#pragma unroll
      for (int r = 0; r < 4; ++r) {
        const size_t row = arow0 + wr * 64 + m * 16 + rb + r;
        const float v = acc[m][n][r];
        Cf[row * N + col] = u2f(f2u(v) & ~1023u);   // tag field = 0
        Cb[row * N + col] = f2bf(v);
      }
    }
}

// ---------------------------------------------------------------------------
// Fused 4-layer wavefront LSTM. 256 WGs (layer=blockIdx>>6, ug=blockIdx&63),
// 256 thr, 1 WG/CU (160KB LDS). Flags (R3-proven) for flow control +
// monotone data tags as staleness backstop:
//   h panels: u32 = ((t+1)<<16)|bf16(h), per-layer ping-pong; accept tag>=t.
//   seq: f32 with 10-bit tag (l*256+t+1) in low mantissa; accept tag>=need.
//   bP: s0(GEMM, tag0) -> s1(L0) -> s3(L2);  bQ: s2(L1), memset0 per launch.
// Per step: poll flags -> h gather/validate/stage 2 halves -> MFMA(B=Wr,LDS)
// -> seq gather/validate 2 halves -> MFMA(B=Wk,128 VGPRs) -> gates ->
// tagged publishes -> barrier -> flag=t+1.
// ---------------------------------------------------------------------------
__global__ __launch_bounds__(256, 1) void fused_lstm_kernel(
    const u16* __restrict__ m0,       // (B*T,1024) bf16 static s0 mirror
    const u16* __restrict__ wrT,      // (4,4096,1024) bf16
    const u16* __restrict__ wkT,      // (4,4096,1024) bf16
    const float* __restrict__ bias,   // (4,4096) f32
    float* __restrict__ bP,           // (B*T,1024) f32: s0 -> s1 -> s3
    float* __restrict__ bQ,           // (B*T,1024) f32: s2
    uint32_t* __restrict__ hpan,      // (4,2,32,1024) u32 tagged h
    uint32_t* __restrict__ flags,     // (4,64) zeroed per launch
    float* __restrict__ out) {        // (2,4,32,1024) f32
  __shared__ __align__(16) u16 Ws[64 * 1024];   // 128 KB Wr slice (swizzled)
  __shared__ __align__(16) u16 Hs[16 * 1024];   // 32 KB stage; gl aliased
  float* gl = (float*)&Hs[0];                   // [4][32][17] f32

  const int tid = threadIdx.x, lane = tid & 63, w = tid >> 6;
  const int l = blockIdx.x >> 6, ug = blockIdx.x & 63, u0 = ug * 16;
  const int r0 = lane & 15, hi = lane >> 4, rb = hi * 4;
  const int gb = tid >> 3, j0 = (tid & 7) * 2;

  const float* bSrc = (l == 2) ? bQ : bP;
  float*       bDst = (l == 1) ? bQ : bP;
  uint32_t* hpL  = hpan + (size_t)l * 65536;
  uint32_t* fOwn = flags + l * 64;
  const uint32_t* fPar = flags + (l - 1) * 64;

  // ---- one-time: Wr slice -> LDS (source-swizzled, linear dest) ----
  {
    const u16* wrL = wrT + (size_t)l * 4096 * 1024;
    for (int it = 0; it < 32; ++it) {
      const int slot = it * 4 + w;
      const int ch = slot * 64 + lane;
      const int r = ch >> 7;
      const int q = (ch & 127) ^ (r & 7);
      gll16(wrL + ((size_t)((r >> 4) * 1024 + u0 + (r & 15))) * 1024 + q * 8,
            (void*)(Ws + slot * 64 * 8));
    }
  }
  // ---- one-time: Wk slice -> registers (all layers) ----
  bf16x8 wkreg[32];
  {
    const u16* wkL = wkT + (size_t)l * 4096 * 1024;
#pragma unroll
    for (int kk = 0; kk < 32; ++kk)
      wkreg[kk] = *(const bf16x8*)(wkL + ((size_t)(w * 1024 + u0 + r0)) * 1024 + kk * 32 + hi * 8);
  }
  const float bv = bias[l * 4096 + w * 1024 + u0 + r0];

  float c0 = 0.f, c1 = 0.f;
  __syncthreads();   // Ws ready (drains gll16 vmcnt)

  for (int t = 0; t < 256; ++t) {
    const uint32_t inT  = (uint32_t)((l - 1) * 256 + t + 1);  // seq-in tag floor (l>=1)
    const uint32_t outT = (uint32_t)(l * 256 + t + 1);        // seq-out tag
    const size_t soOff = ((size_t)(gb * 256 + t)) * 1024 + u0 + j0;

    // ---- flow-control poll (R3-proven mechanism) ----
    if (t > 0 || l > 0) {
      while (true) {
        bool ok = true;
        if (t > 0) {
          uint32_t own = __hip_atomic_load(fOwn + lane, __ATOMIC_RELAXED, __HIP_MEMORY_SCOPE_AGENT);
          ok = __all(own >= (uint32_t)t);
        }
        if (ok && l) {
          uint32_t par = __hip_atomic_load(fPar + lane, __ATOMIC_RELAXED, __HIP_MEMORY_SCOPE_AGENT);
          ok = __all(par >= (uint32_t)(t + 1));
        }
        if (ok) break;
        __builtin_amdgcn_s_sleep(1);
      }
    }

    // own-slice residual: issue early (validated later)
    f32x2 so = {0.f, 0.f};
    u32x2 sot = {0u, 0u};
    if (l == 1 || l == 2) sot = ldg2u(bSrc + soOff);
    else if (l == 0)      so  = *(const f32x2*)(bP + soOff);

    f32x4 acc0 = (f32x4){bv, bv, bv, bv};
    f32x4 acc1 = acc0;

    // ================= h phase =================
    if (t > 0) {
      const uint32_t* hsrc = hpL + (size_t)((t - 1) & 1) * 32768;
      const uint32_t need = (uint32_t)t;
#pragma unroll
      for (int half = 0; half < 2; ++half) {
        u32x4 ga[8], gbv[8];
#pragma unroll
        for (int s = 0; s < 8; ++s) {
          const int c = (half * 8 + s) * 256 + tid;
          const int row = c >> 7, q = c & 127;
          const uint32_t* P = hsrc + row * 1024 + q * 8;
          ga[s] = ldg4u(P); gbv[s] = ldg4u(P + 4);
        }
        asm volatile("s_waitcnt vmcnt(0)" ::: "memory");
        __builtin_amdgcn_sched_barrier(0);
#pragma unroll
        for (int s = 0; s < 8; ++s) {
          const int c = (half * 8 + s) * 256 + tid;
          const int row = c >> 7, q = c & 127;
          const uint32_t* P = hsrc + row * 1024 + q * 8;
          while (true) {
            uint32_t mn = umin2(umin2(umin2(ga[s].x >> 16, ga[s].y >> 16),
                                      umin2(ga[s].z >> 16, ga[s].w >> 16)),
                                umin2(umin2(gbv[s].x >> 16, gbv[s].y >> 16),
                                      umin2(gbv[s].z >> 16, gbv[s].w >> 16)));
            if (!__any(mn < need)) break;
            __builtin_amdgcn_s_sleep(1);
            ga[s] = ldg4u(P); gbv[s] = ldg4u(P + 4);
            asm volatile("s_waitcnt vmcnt(0)" ::: "memory");
            __builtin_amdgcn_sched_barrier(0);
          }
          u32x4 pk;
          pk.x = (ga[s].x & 0xFFFFu) | (ga[s].y << 16);
          pk.y = (ga[s].z & 0xFFFFu) | (ga[s].w << 16);
          pk.z = (gbv[s].x & 0xFFFFu) | (gbv[s].y << 16);
          pk.w = (gbv[s].z & 0xFFFFu) | (gbv[s].w << 16);
          *(u32x4*)(Hs + (size_t)(row & 15) * 1024 + (size_t)(q ^ (row & 7)) * 8) = pk;
        }
        __syncthreads();
        {
          f32x4 a_ = half ? acc1 : acc0;
#pragma unroll
          for (int kk = 0; kk < 32; ++kk) {
            const int q = kk * 4 + hi, sw = (q ^ (r0 & 7)) * 8;
            bf16x8 av = *(const bf16x8*)(Hs + (size_t)r0 * 1024 + sw);
            bf16x8 bw = *(const bf16x8*)(Ws + (size_t)(w * 16 + r0) * 1024 + sw);
            a_ = __builtin_amdgcn_mfma_f32_16x16x32_bf16(av, bw, a_, 0, 0, 0);
          }
          if (half) acc1 = a_; else acc0 = a_;
        }
        __syncthreads();
      }
    }

    // ================= seq phase =================
#pragma unroll
    for (int half = 0; half < 2; ++half) {
      if (l) {
        u32x4 ga[8], gbv[8];
#pragma unroll
        for (int s = 0; s < 8; ++s) {
          const int c = (half * 8 + s) * 256 + tid;
          const int row = c >> 7, q = c & 127;
          const float* P = bSrc + ((size_t)(row * 256 + t)) * 1024 + q * 8;
          ga[s] = ldg4u(P); gbv[s] = ldg4u(P + 4);
        }
        asm volatile("s_waitcnt vmcnt(0)" ::: "memory");
        __builtin_amdgcn_sched_barrier(0);
#pragma unroll
        for (int s = 0; s < 8; ++s) {
          const int c = (half * 8 + s) * 256 + tid;
          const int row = c >> 7, q = c & 127;
          const float* P = bSrc + ((size_t)(row * 256 + t)) * 1024 + q * 8;
          while (true) {
            uint32_t mn = umin2(umin2(umin2(ga[s].x & 1023u, ga[s].y & 1023u),
                                      umin2(ga[s].z & 1023u, ga[s].w & 1023u)),
                                umin2(umin2(gbv[s].x & 1023u, gbv[s].y & 1023u),
                                      umin2(gbv[s].z & 1023u, gbv[s].w & 1023u)));
            if (!__any(mn < inT)) break;
            __builtin_amdgcn_s_sleep(1);
            ga[s] = ldg4u(P); gbv[s] = ldg4u(P + 4);
            asm volatile("s_waitcnt vmcnt(0)" ::: "memory");
            __builtin_amdgcn_sched_barrier(0);
          }
          u32x4 pk;
          pk.x = cvt2(u2f(ga[s].x), u2f(ga[s].y));
          pk.y = cvt2(u2f(ga[s].z), u2f(ga[s].w));
          pk.z = cvt2(u2f(gbv[s].x), u2f(gbv[s].y));
          pk.w = cvt2(u2f(gbv[s].z), u2f(gbv[s].w));
          *(u32x4*)(Hs + (size_t)(row & 15) * 1024 + (size_t)(q ^ (row & 7)) * 8) = pk;
        }
      } else {
#pragma unroll
        for (int s = 0; s < 8; ++s) {
          const int c = (half * 8 + s) * 256 + tid;
          const int row = c >> 7, q = c & 127;
          u32x4 pk = *(const u32x4*)(m0 + ((size_t)(row * 256 + t)) * 1024 + q * 8);
          *(u32x4*)(Hs + (size_t)(row & 15) * 1024 + (size_t)(q ^ (row & 7)) * 8) = pk;
        }
      }
      __syncthreads();
      {
        f32x4 a_ = half ? acc1 : acc0;
#pragma unroll
        for (int kk = 0; kk < 32; ++kk) {
          const int q = kk * 4 + hi, sw = (q ^ (r0 & 7)) * 8;
          bf16x8 av = *(const bf16x8*)(Hs + (size_t)r0 * 1024 + sw);
          a_ = __builtin_amdgcn_mfma_f32_16x16x32_bf16(av, wkreg[kk], a_, 0, 0, 0);
        }
        if (half) acc1 = a_; else acc0 = a_;
      }
      __syncthreads();
    }

    // validate own-slice residual (l=1,2); per-lane retry
    if (l == 1 || l == 2) {
      while ((sot.x & 1023u) < inT || (sot.y & 1023u) < inT) {
        __builtin_amdgcn_s_sleep(1);
        sot = ldg2u(bSrc + soOff);
        asm volatile("s_waitcnt vmcnt(0)" ::: "memory");
        __builtin_amdgcn_sched_barrier(0);
      }
      so.x = u2f(sot.x & ~1023u);
      so.y = u2f(sot.y & ~1023u);
    }

    // ---- D frag -> gl (col=lane&15 unit, row=(lane>>4)*4+reg batch) ----
#pragma unroll
    for (int m = 0; m < 2; ++m) {
      f32x4 a_ = m ? acc1 : acc0;
#pragma unroll
      for (int r = 0; r < 4; ++r)
        gl[(w * 32 + m * 16 + rb + r) * 17 + r0] = a_[r];
    }
    __syncthreads();

    // ---- gates + cell update + tagged publishes ----
    float hv0, hv1;
    {
      const float gi0 = gl[(0  + gb) * 17 + j0], gi1 = gl[(0  + gb) * 17 + j0 + 1];
      const float gf0 = gl[(32 + gb) * 17 + j0], gf1 = gl[(32 + gb) * 17 + j0 + 1];
      const float gc0 = gl[(64 + gb) * 17 + j0], gc1 = gl[(64 + gb) * 17 + j0 + 1];
      const float go0 = gl[(96 + gb) * 17 + j0], go1 = gl[(96 + gb) * 17 + j0 + 1];
      c0 = sigmoidf(gf0) * c0 + sigmoidf(gi0) * tanhf(gc0);
      c1 = sigmoidf(gf1) * c1 + sigmoidf(gi1) * tanhf(gc1);
      hv0 = sigmoidf(go0) * tanhf(c0);
      hv1 = sigmoidf(go1) * tanhf(c1);
    }
    if (t == 255) {
      out[(size_t)l * 32768 + (size_t)gb * 1024 + u0 + j0]           = hv0;
      out[(size_t)l * 32768 + (size_t)gb * 1024 + u0 + j0 + 1]       = hv1;
      out[(size_t)(4 + l) * 32768 + (size_t)gb * 1024 + u0 + j0]     = c0;
      out[(size_t)(4 + l) * 32768 + (size_t)gb * 1024 + u0 + j0 + 1] = c1;
    } else {
      const uint32_t tg = (uint32_t)(t + 1) << 16;
      const uint64_t pk = (uint64_t)(tg | f2bf(hv0)) | ((uint64_t)(tg | f2bf(hv1)) << 32);
      __hip_atomic_store((uint64_t*)(hpL + (size_t)(t & 1) * 32768 + gb * 1024 + u0 + j0),
                         pk, __ATOMIC_RELAXED, __HIP_MEMORY_SCOPE_AGENT);
    }
    if (l < 3) {
      const uint32_t b0 = (f2u(so.x + hv0) & ~1023u) | outT;
      const uint32_t b1 = (f2u(so.y + hv1) & ~1023u) | outT;
      const uint64_t pk = (uint64_t)b0 | ((uint64_t)b1 << 32);
      __hip_atomic_store((uint64_t*)(bDst + soOff), pk,
                         __ATOMIC_RELAXED, __HIP_MEMORY_SCOPE_AGENT);
    }

    __syncthreads();   // drain publishes (vmcnt) + gl reads done
    if (tid == 0)
      __hip_atomic_store(fOwn + ug, (uint32_t)(t + 1),
                         __ATOMIC_RELAXED, __HIP_MEMORY_SCOPE_AGENT);
  }
}

// ---------------------------------------------------------------------------
extern "C" void kernel_launch(void* const* d_in, const int* in_sizes, int n_in,
                              void* d_out, int out_size, void* d_ws, size_t ws_size,
                              hipStream_t stream) {
  const float* x     = (const float*)d_in[0];   // (32,256,512)
  const float* Wskip = (const float*)d_in[1];   // (512,1024)
  const float* Wk    = (const float*)d_in[2];   // (4,1024,4096)
  const float* Wr    = (const float*)d_in[3];   // (4,1024,4096)
  const float* bias  = (const float*)d_in[4];   // (4,4096)
  float* out = (float*)d_out;

  char* ws = (char*)d_ws;
  size_t o = 0;
  auto carve = [&](size_t bytes) -> char* {
    char* p = ws + o;
    o += (bytes + 255) & ~(size_t)255;
    return p;
  };
  u16*      xbf   = (u16*)     carve((size_t)8192 * 512 * 2);
  u16*      wskT  = (u16*)     carve((size_t)1024 * 512 * 2);
  u16*      wkT   = (u16*)     carve((size_t)4 * 4096 * 1024 * 2);
  u16*      wrT   = (u16*)     carve((size_t)4 * 4096 * 1024 * 2);
  float*    bP    = (float*)   carve((size_t)8192 * 1024 * 4);
  float*    bQ    = (float*)   carve((size_t)8192 * 1024 * 4);
  u16*      m0    = (u16*)     carve((size_t)8192 * 1024 * 2);
  uint32_t* hpan  = (uint32_t*)carve((size_t)4 * 2 * 32 * 1024 * 4);
  uint32_t* flags = (uint32_t*)carve((size_t)4 * 64 * 4);

  // ---- per-launch resets (replay safety: erase stale tags) ----
  hipMemsetAsync(flags, 0, 4 * 64 * 4, stream);
  hipMemsetAsync(hpan, 0, (size_t)4 * 2 * 32 * 1024 * 4, stream);
  hipMemsetAsync(bQ, 0, (size_t)8192 * 1024 * 4, stream);

  // ---- prep ----
  convert_bf16_kernel<<<4096, 256, 0, stream>>>(x, xbf, 8192 * 512);
  dim3 tb(32, 32);
  transpose_to_bf16<<<dim3(1024 / 32, 512 / 32), tb, 0, stream>>>(Wskip, wskT, 512, 1024);
  for (int l = 0; l < 4; ++l) {
    transpose_to_bf16<<<dim3(4096 / 32, 1024 / 32), tb, 0, stream>>>(
        Wk + (size_t)l * 1024 * 4096, wkT + (size_t)l * 4096 * 1024, 1024, 4096);
    transpose_to_bf16<<<dim3(4096 / 32, 1024 / 32), tb, 0, stream>>>(
        Wr + (size_t)l * 1024 * 4096, wrT + (size_t)l * 4096 * 1024, 1024, 4096);
  }

  // s0 = x @ W_skip : f32 (tag field 0) -> bP, bf16 mirror -> m0
  gemm_bt_kernel<<<dim3(1024 / 128, 8192 / 128), 256, 0, stream>>>(
      xbf, wskT, bP, m0, 8192, 1024, 512);

  // ---- fused 4-layer wavefront recurrence (single dispatch) ----
  fused_lstm_kernel<<<256, 256, 0, stream>>>(m0, wrT, wkT, bias, bP, bQ,
                                             hpan, flags, out);
}